// Round 18
// baseline (104.002 us; speedup 1.0000x reference)
//
#include <hip/hip_runtime.h>
#include <hip/hip_bf16.h>

#define N_ROWS 8192
#define D_DIM  512
#define NSTEPS 8    // K-steps of BK=64 fp8 bytes

typedef __attribute__((ext_vector_type(4))) int   i32x4;
typedef __attribute__((ext_vector_type(8))) int   i32x8;
typedef __attribute__((ext_vector_type(16))) float f32x16;

typedef const __attribute__((address_space(1))) void* gptr_t;
typedef __attribute__((address_space(3))) void* lptr_t;

static __device__ __forceinline__ void gload16(const void* g, void* l) {
    __builtin_amdgcn_global_load_lds((gptr_t)g, (lptr_t)l, 16, 0, 0);
}
#define VMCNT(n)  asm volatile("s_waitcnt vmcnt(" #n ")" ::: "memory")
#define BARRIER() __builtin_amdgcn_s_barrier()
#define SCHED0()  __builtin_amdgcn_sched_barrier(0)

// One wave per row-index i: L2-normalize cxr_i and ehr_i, write fp8 e4m3,
// and compute diag_i = dot(cxr_i,ehr_i)*ia*ib/temp (full fp32) in one pass.
__global__ void normdiag_kernel(const float* __restrict__ cxr, const float* __restrict__ ehr,
                                unsigned char* __restrict__ Ab, unsigned char* __restrict__ Bb,
                                const float* __restrict__ temp, float* __restrict__ dg) {
    const int row = blockIdx.x * 4 + (threadIdx.x >> 6);
    const int lane = threadIdx.x & 63;
    const float4* a4 = (const float4*)(cxr + (size_t)row * D_DIM + lane * 8);
    const float4* b4 = (const float4*)(ehr + (size_t)row * D_DIM + lane * 8);
    float4 a0 = a4[0], a1 = a4[1];
    float4 b0 = b4[0], b1 = b4[1];
    float sa = a0.x*a0.x + a0.y*a0.y + a0.z*a0.z + a0.w*a0.w
             + a1.x*a1.x + a1.y*a1.y + a1.z*a1.z + a1.w*a1.w;
    float sb = b0.x*b0.x + b0.y*b0.y + b0.z*b0.z + b0.w*b0.w
             + b1.x*b1.x + b1.y*b1.y + b1.z*b1.z + b1.w*b1.w;
    float dt = a0.x*b0.x + a0.y*b0.y + a0.z*b0.z + a0.w*b0.w
             + a1.x*b1.x + a1.y*b1.y + a1.z*b1.z + a1.w*b1.w;
#pragma unroll
    for (int s = 1; s < 64; s <<= 1) {
        sa += __shfl_xor(sa, s);
        sb += __shfl_xor(sb, s);
        dt += __shfl_xor(dt, s);
    }
    const float ia = 1.0f / sqrtf(fmaxf(sa, 1e-16f));
    const float ib = 1.0f / sqrtf(fmaxf(sb, 1e-16f));
    if (lane == 0) dg[row] = dt * ia * ib / temp[0];
    float va[8] = {a0.x, a0.y, a0.z, a0.w, a1.x, a1.y, a1.z, a1.w};
    float vb[8] = {b0.x, b0.y, b0.z, b0.w, b1.x, b1.y, b1.z, b1.w};
    int aw0 = __builtin_amdgcn_cvt_pk_fp8_f32(va[0]*ia, va[1]*ia, 0, false);
    aw0     = __builtin_amdgcn_cvt_pk_fp8_f32(va[2]*ia, va[3]*ia, aw0, true);
    int aw1 = __builtin_amdgcn_cvt_pk_fp8_f32(va[4]*ia, va[5]*ia, 0, false);
    aw1     = __builtin_amdgcn_cvt_pk_fp8_f32(va[6]*ia, va[7]*ia, aw1, true);
    int bw0 = __builtin_amdgcn_cvt_pk_fp8_f32(vb[0]*ib, vb[1]*ib, 0, false);
    bw0     = __builtin_amdgcn_cvt_pk_fp8_f32(vb[2]*ib, vb[3]*ib, bw0, true);
    int bw1 = __builtin_amdgcn_cvt_pk_fp8_f32(vb[4]*ib, vb[5]*ib, 0, false);
    bw1     = __builtin_amdgcn_cvt_pk_fp8_f32(vb[6]*ib, vb[7]*ib, bw1, true);
    *(int2*)(Ab + (size_t)row * D_DIM + lane * 8) = make_int2(aw0, aw1);
    *(int2*)(Bb + (size_t)row * D_DIM + lane * 8) = make_int2(bw0, bw1);
}

// by-value 32-byte fragment from two 16-B LDS slots (the r9/r10 no-alloca idiom)
static __device__ __forceinline__ i32x8 ld2(const unsigned char* p0, const unsigned char* p1) {
    i32x4 lo = *(const i32x4*)p0;
    i32x4 hi = *(const i32x4*)(p1);
    return (i32x8){lo[0], lo[1], lo[2], lo[3], hi[0], hi[1], hi[2], hi[3]};
}

// fp8 128x128 GEMM, E + E^T per wave (lane-local row AND col sums). Exact r14
// 85us main loop: ring-3 LDS, counted VMCNT(2), 8 waves (2x4), wave tile 64x32,
// LDS-staged epilogue sums (r16 A/B: direct global atomics cost +3-4us).
// r18 deltas vs r14: exp2(fma) epilogue math only.
__global__ __launch_bounds__(512, 2) void gemm_lse_kernel(
        const unsigned char* __restrict__ A, const unsigned char* __restrict__ B,
        const float* __restrict__ temp,
        float* __restrict__ row_sum, float* __restrict__ col_sum) {
    __shared__ unsigned char As[3][8192];    // [buf][128 rows][64 B] = 3 x 8 KB
    __shared__ unsigned char Bs[3][8192];
    __shared__ float rs_l[128];
    __shared__ float cs_l[128];

    const int tid = threadIdx.x;
    const int lane = tid & 63;
    const int wid = tid >> 6;                 // 8 waves
    const int bm = blockIdx.x & 63;           // bm-major for B-panel L2 reuse
    const int bn = blockIdx.x >> 6;
    const int wm = wid >> 2, wn = wid & 3;    // wave tile 64x32

    if (tid < 128) rs_l[tid] = 0.f;
    else if (tid < 256) cs_l[tid - 128] = 0.f;

    // staging: wave stages A rows wid*16..+16 and B rows wid*16..+16 (1 gload
    // each). Linear LDS dest; T2 source swizzle: lane l -> row base+(l>>2),
    // slot l&3, source slot (l&3)^((l>>3)&3).
    const int swz = ((lane & 3) ^ ((lane >> 3) & 3)) * 16;
    const unsigned char* gA = A + (size_t)(bm * 128 + wid * 16 + (lane >> 2)) * D_DIM + swz;
    const unsigned char* gB = B + (size_t)(bn * 128 + wid * 16 + (lane >> 2)) * D_DIM + swz;

#define STG(d, st) do { \
    gload16(gA + (st) * 64, &As[d][(wid * 16) * 64]); \
    gload16(gB + (st) * 64, &Bs[d][(wid * 16) * 64]); } while (0)

    // fragment reads: lane covers row base+c31, k-half h2 (32 B = 2 b128).
    // LDS slot of global slot g at row r: g ^ ((r>>1)&3); (r>>1)&3 = (c31>>1)&3.
    const int c31 = lane & 31, h2 = lane >> 5;
    const int so0 = (((2 * h2) ^ ((c31 >> 1) & 3)) & 3) * 16;

    f32x16 acc[2] = {};    // E quadrants (mi)
    f32x16 accT[2] = {};   // E^T quadrants (mi)
    const int sc = 0x7F7F7F7F;   // E8M0 127 -> scale 1.0

    // prologue: stage steps 0,1 (2 gloads/wave each); drain step 0, keep 1 flying
    STG(0, 0);
    STG(1, 1);
    VMCNT(2);
    BARRIER(); SCHED0();

#pragma unroll
    for (int s = 0; s < NSTEPS; ++s) {
        const int d = s % 3;
        if (s + 2 < NSTEPS) STG((s + 2) % 3, s + 2);

        i32x8 Af0, Af1, Bf;
        {
            const unsigned char* rp = &As[d][(wm * 64 + c31) * 64];
            Af0 = ld2(rp + so0, rp + (so0 ^ 16));
            rp += 32 * 64;
            Af1 = ld2(rp + so0, rp + (so0 ^ 16));
            const unsigned char* bp = &Bs[d][(wn * 32 + c31) * 64];
            Bf = ld2(bp + so0, bp + (so0 ^ 16));
        }
        acc[0]  = __builtin_amdgcn_mfma_scale_f32_32x32x64_f8f6f4(Af0, Bf, acc[0],  0, 0, 0, sc, 0, sc);
        acc[1]  = __builtin_amdgcn_mfma_scale_f32_32x32x64_f8f6f4(Af1, Bf, acc[1],  0, 0, 0, sc, 0, sc);
        accT[0] = __builtin_amdgcn_mfma_scale_f32_32x32x64_f8f6f4(Bf, Af0, accT[0], 0, 0, 0, sc, 0, sc);
        accT[1] = __builtin_amdgcn_mfma_scale_f32_32x32x64_f8f6f4(Bf, Af1, accT[1], 0, 0, 0, sc, 0, sc);

        // boundary: certify step s+1 landed for all waves; keep s+2 flying
        if (s <= NSTEPS - 3)       { VMCNT(2); BARRIER(); SCHED0(); }
        else if (s == NSTEPS - 2)  { VMCNT(0); BARRIER(); SCHED0(); }
    }

    // ---- epilogue: lane-local sums -> LDS-staged block sums ----
    // exp((a-1)/T) = exp2(a*c1 + c0), c1 = log2e/T, c0 = -c1
    // C/D 32x32 layout: col = lane&31, row = (reg&3) + 8*(reg>>2) + 4*(lane>>5)
    const float c1 = 1.4426950408889634f / temp[0];
    const float c0 = -c1;
    const bool dBlk = (bm == bn);

    // E: lane owns col j = wn*32 + c31; rows i = wm*64 + mi*32 + rowof(r,h2)
    float csum = 0.f;
#pragma unroll
    for (int mi = 0; mi < 2; ++mi) {
        f32x16 a = acc[mi];
#pragma unroll
        for (int r = 0; r < 16; ++r) {
            float e = exp2f(fmaf(a[r], c1, c0));
            if (dBlk) {
                int grow = wm * 64 + mi * 32 + (r & 3) + 8 * (r >> 2) + 4 * h2;
                int gcol = wn * 32 + c31;
                if (grow == gcol) e = 0.f;
            }
            csum += e;
        }
    }
    csum += __shfl_xor(csum, 32);
    if (h2 == 0) atomicAdd(&cs_l[wn * 32 + c31], csum);

    // E^T: lane owns col i = wm*64 + mi*32 + c31; rows j = wn*32 + rowof(r,h2)
#pragma unroll
    for (int mi = 0; mi < 2; ++mi) {
        f32x16 a = accT[mi];
        float rsum = 0.f;
#pragma unroll
        for (int r = 0; r < 16; ++r) {
            float e = exp2f(fmaf(a[r], c1, c0));
            if (dBlk) {
                int grow = wn * 32 + (r & 3) + 8 * (r >> 2) + 4 * h2;
                int gcol = wm * 64 + mi * 32 + c31;
                if (grow == gcol) e = 0.f;
            }
            rsum += e;
        }
        rsum += __shfl_xor(rsum, 32);
        if (h2 == 0) atomicAdd(&rs_l[wm * 64 + mi * 32 + c31], rsum);
    }
    __syncthreads();
    if (tid < 128) atomicAdd(&row_sum[bm * 128 + tid], rs_l[tid]);
    else if (tid < 256) atomicAdd(&col_sum[bn * 128 + (tid - 128)], cs_l[tid - 128]);
}

// loss = mean_i [ 2M + log(rs_i) + log(cs_i) - 2*diag_i ],  M = 1/temp
// 16 blocks x 512 threads; block sums atomicAdd into out[0] (pre-zeroed).
__global__ void finalize_kernel(const float* __restrict__ rs, const float* __restrict__ cs,
                                const float* __restrict__ dg, const float* __restrict__ temp,
                                float* __restrict__ out) {
    const float M = 1.0f / temp[0];
    const int i = blockIdx.x * 512 + threadIdx.x;
    float acc = 2.f * M + __logf(rs[i]) + __logf(cs[i]) - 2.f * dg[i];
#pragma unroll
    for (int s = 1; s < 64; s <<= 1) acc += __shfl_xor(acc, s);
    __shared__ float wsum[8];
    if ((threadIdx.x & 63) == 0) wsum[threadIdx.x >> 6] = acc;
    __syncthreads();
    if (threadIdx.x == 0) {
        float t = 0.f;
#pragma unroll
        for (int w = 0; w < 8; ++w) t += wsum[w];
        atomicAdd(out, t / (float)N_ROWS);
    }
}

extern "C" void kernel_launch(void* const* d_in, const int* in_sizes, int n_in,
                              void* d_out, int out_size, void* d_ws, size_t ws_size,
                              hipStream_t stream) {
    const float* cxr = (const float*)d_in[0];
    const float* ehr = (const float*)d_in[1];
    const float* temp = (const float*)d_in[2];
    float* out = (float*)d_out;

    char* ws = (char*)d_ws;
    unsigned char* Ab = (unsigned char*)ws;                        // 4 MB
    unsigned char* Bb = (unsigned char*)(ws + 4u * 1024 * 1024);   // 4 MB
    float* rs = (float*)(ws + 8u * 1024 * 1024);
    float* cs = rs + N_ROWS;
    float* dg = cs + N_ROWS;

    hipMemsetAsync(rs, 0, 2 * N_ROWS * sizeof(float), stream);
    hipMemsetAsync(out, 0, sizeof(float), stream);
    normdiag_kernel<<<dim3(N_ROWS / 4), 256, 0, stream>>>(cxr, ehr, Ab, Bb, temp, dg);
    gemm_lse_kernel<<<dim3(64 * 64), 512, 0, stream>>>(Ab, Bb, temp, rs, cs);
    finalize_kernel<<<dim3(16), 512, 0, stream>>>(rs, cs, dg, temp, out);
}

// Round 19
// 97.209 us; speedup vs baseline: 1.0699x; 1.0699x over previous
//
#include <hip/hip_runtime.h>
#include <hip/hip_bf16.h>

#define N_ROWS 8192
#define D_DIM  512
#define NSTEPS 8    // K-steps of BK=64 fp8 bytes

typedef __attribute__((ext_vector_type(4))) int   i32x4;
typedef __attribute__((ext_vector_type(8))) int   i32x8;
typedef __attribute__((ext_vector_type(16))) float f32x16;

typedef const __attribute__((address_space(1))) void* gptr_t;
typedef __attribute__((address_space(3))) void* lptr_t;

static __device__ __forceinline__ void gload16(const void* g, void* l) {
    __builtin_amdgcn_global_load_lds((gptr_t)g, (lptr_t)l, 16, 0, 0);
}
#define VMCNT(n)  asm volatile("s_waitcnt vmcnt(" #n ")" ::: "memory")
#define BARRIER() __builtin_amdgcn_s_barrier()
#define SCHED0()  __builtin_amdgcn_sched_barrier(0)

// One wave per row-index i: L2-normalize cxr_i and ehr_i, write fp8 e4m3,
// and compute diag_i = dot(cxr_i,ehr_i)*ia*ib/temp (full fp32) in one pass.
__global__ void normdiag_kernel(const float* __restrict__ cxr, const float* __restrict__ ehr,
                                unsigned char* __restrict__ Ab, unsigned char* __restrict__ Bb,
                                const float* __restrict__ temp, float* __restrict__ dg) {
    const int row = blockIdx.x * 4 + (threadIdx.x >> 6);
    const int lane = threadIdx.x & 63;
    const float4* a4 = (const float4*)(cxr + (size_t)row * D_DIM + lane * 8);
    const float4* b4 = (const float4*)(ehr + (size_t)row * D_DIM + lane * 8);
    float4 a0 = a4[0], a1 = a4[1];
    float4 b0 = b4[0], b1 = b4[1];
    float sa = a0.x*a0.x + a0.y*a0.y + a0.z*a0.z + a0.w*a0.w
             + a1.x*a1.x + a1.y*a1.y + a1.z*a1.z + a1.w*a1.w;
    float sb = b0.x*b0.x + b0.y*b0.y + b0.z*b0.z + b0.w*b0.w
             + b1.x*b1.x + b1.y*b1.y + b1.z*b1.z + b1.w*b1.w;
    float dt = a0.x*b0.x + a0.y*b0.y + a0.z*b0.z + a0.w*b0.w
             + a1.x*b1.x + a1.y*b1.y + a1.z*b1.z + a1.w*b1.w;
#pragma unroll
    for (int s = 1; s < 64; s <<= 1) {
        sa += __shfl_xor(sa, s);
        sb += __shfl_xor(sb, s);
        dt += __shfl_xor(dt, s);
    }
    const float ia = 1.0f / sqrtf(fmaxf(sa, 1e-16f));
    const float ib = 1.0f / sqrtf(fmaxf(sb, 1e-16f));
    if (lane == 0) dg[row] = dt * ia * ib / temp[0];
    float va[8] = {a0.x, a0.y, a0.z, a0.w, a1.x, a1.y, a1.z, a1.w};
    float vb[8] = {b0.x, b0.y, b0.z, b0.w, b1.x, b1.y, b1.z, b1.w};
    int aw0 = __builtin_amdgcn_cvt_pk_fp8_f32(va[0]*ia, va[1]*ia, 0, false);
    aw0     = __builtin_amdgcn_cvt_pk_fp8_f32(va[2]*ia, va[3]*ia, aw0, true);
    int aw1 = __builtin_amdgcn_cvt_pk_fp8_f32(va[4]*ia, va[5]*ia, 0, false);
    aw1     = __builtin_amdgcn_cvt_pk_fp8_f32(va[6]*ia, va[7]*ia, aw1, true);
    int bw0 = __builtin_amdgcn_cvt_pk_fp8_f32(vb[0]*ib, vb[1]*ib, 0, false);
    bw0     = __builtin_amdgcn_cvt_pk_fp8_f32(vb[2]*ib, vb[3]*ib, bw0, true);
    int bw1 = __builtin_amdgcn_cvt_pk_fp8_f32(vb[4]*ib, vb[5]*ib, 0, false);
    bw1     = __builtin_amdgcn_cvt_pk_fp8_f32(vb[6]*ib, vb[7]*ib, bw1, true);
    *(int2*)(Ab + (size_t)row * D_DIM + lane * 8) = make_int2(aw0, aw1);
    *(int2*)(Bb + (size_t)row * D_DIM + lane * 8) = make_int2(bw0, bw1);
}

// by-value 32-byte fragment from two 16-B LDS slots (the r9/r10 no-alloca idiom)
static __device__ __forceinline__ i32x8 ld2(const unsigned char* p0, const unsigned char* p1) {
    i32x4 lo = *(const i32x4*)p0;
    i32x4 hi = *(const i32x4*)(p1);
    return (i32x8){lo[0], lo[1], lo[2], lo[3], hi[0], hi[1], hi[2], hi[3]};
}

// fp8 128x128 GEMM, E + E^T per wave (lane-local row AND col sums) — the r14
// 85us configuration, byte-for-byte: ring-3 LDS, counted VMCNT(2), 8 waves
// (2x4), wave tile 64x32, __expf epilogue, LDS-staged block sums.
__global__ __launch_bounds__(512, 2) void gemm_lse_kernel(
        const unsigned char* __restrict__ A, const unsigned char* __restrict__ B,
        const float* __restrict__ temp,
        float* __restrict__ row_sum, float* __restrict__ col_sum) {
    __shared__ unsigned char As[3][8192];    // [buf][128 rows][64 B] = 3 x 8 KB
    __shared__ unsigned char Bs[3][8192];
    __shared__ float rs_l[128];
    __shared__ float cs_l[128];

    const int tid = threadIdx.x;
    const int lane = tid & 63;
    const int wid = tid >> 6;                 // 8 waves
    const int bm = blockIdx.x & 63;           // bm-major for B-panel L2 reuse
    const int bn = blockIdx.x >> 6;
    const int wm = wid >> 2, wn = wid & 3;    // wave tile 64x32

    if (tid < 128) rs_l[tid] = 0.f;
    else if (tid < 256) cs_l[tid - 128] = 0.f;

    // staging: wave stages A rows wid*16..+16 and B rows wid*16..+16 (1 gload
    // each). Linear LDS dest; T2 source swizzle: lane l -> row base+(l>>2),
    // slot l&3, source slot (l&3)^((l>>3)&3).
    const int swz = ((lane & 3) ^ ((lane >> 3) & 3)) * 16;
    const unsigned char* gA = A + (size_t)(bm * 128 + wid * 16 + (lane >> 2)) * D_DIM + swz;
    const unsigned char* gB = B + (size_t)(bn * 128 + wid * 16 + (lane >> 2)) * D_DIM + swz;

#define STG(d, st) do { \
    gload16(gA + (st) * 64, &As[d][(wid * 16) * 64]); \
    gload16(gB + (st) * 64, &Bs[d][(wid * 16) * 64]); } while (0)

    // fragment reads: lane covers row base+c31, k-half h2 (32 B = 2 b128).
    // LDS slot of global slot g at row r: g ^ ((r>>1)&3); (r>>1)&3 = (c31>>1)&3.
    const int c31 = lane & 31, h2 = lane >> 5;
    const int so0 = (((2 * h2) ^ ((c31 >> 1) & 3)) & 3) * 16;

    f32x16 acc[2] = {};    // E quadrants (mi)
    f32x16 accT[2] = {};   // E^T quadrants (mi)
    const int sc = 0x7F7F7F7F;   // E8M0 127 -> scale 1.0

    // prologue: stage steps 0,1 (2 gloads/wave each); drain step 0, keep 1 flying
    STG(0, 0);
    STG(1, 1);
    VMCNT(2);
    BARRIER(); SCHED0();

#pragma unroll
    for (int s = 0; s < NSTEPS; ++s) {
        const int d = s % 3;
        if (s + 2 < NSTEPS) STG((s + 2) % 3, s + 2);

        i32x8 Af0, Af1, Bf;
        {
            const unsigned char* rp = &As[d][(wm * 64 + c31) * 64];
            Af0 = ld2(rp + so0, rp + (so0 ^ 16));
            rp += 32 * 64;
            Af1 = ld2(rp + so0, rp + (so0 ^ 16));
            const unsigned char* bp = &Bs[d][(wn * 32 + c31) * 64];
            Bf = ld2(bp + so0, bp + (so0 ^ 16));
        }
        acc[0]  = __builtin_amdgcn_mfma_scale_f32_32x32x64_f8f6f4(Af0, Bf, acc[0],  0, 0, 0, sc, 0, sc);
        acc[1]  = __builtin_amdgcn_mfma_scale_f32_32x32x64_f8f6f4(Af1, Bf, acc[1],  0, 0, 0, sc, 0, sc);
        accT[0] = __builtin_amdgcn_mfma_scale_f32_32x32x64_f8f6f4(Bf, Af0, accT[0], 0, 0, 0, sc, 0, sc);
        accT[1] = __builtin_amdgcn_mfma_scale_f32_32x32x64_f8f6f4(Bf, Af1, accT[1], 0, 0, 0, sc, 0, sc);

        // boundary: certify step s+1 landed for all waves; keep s+2 flying
        if (s <= NSTEPS - 3)       { VMCNT(2); BARRIER(); SCHED0(); }
        else if (s == NSTEPS - 2)  { VMCNT(0); BARRIER(); SCHED0(); }
    }

    // ---- epilogue: lane-local sums, no shuffle storm (r14 form, __expf) ----
    // C/D 32x32 layout: col = lane&31, row = (reg&3) + 8*(reg>>2) + 4*(lane>>5)
    const float invT = 1.0f / temp[0];
    const bool dBlk = (bm == bn);

    // E: lane owns col j = wn*32 + c31; rows i = wm*64 + mi*32 + rowof(r,h2)
    float csum = 0.f;
#pragma unroll
    for (int mi = 0; mi < 2; ++mi) {
        f32x16 a = acc[mi];
#pragma unroll
        for (int r = 0; r < 16; ++r) {
            float e = __expf((a[r] - 1.0f) * invT);
            if (dBlk) {
                int grow = wm * 64 + mi * 32 + (r & 3) + 8 * (r >> 2) + 4 * h2;
                int gcol = wn * 32 + c31;
                if (grow == gcol) e = 0.f;
            }
            csum += e;
        }
    }
    csum += __shfl_xor(csum, 32);
    if (h2 == 0) atomicAdd(&cs_l[wn * 32 + c31], csum);

    // E^T: lane owns col i = wm*64 + mi*32 + c31; rows j = wn*32 + rowof(r,h2)
#pragma unroll
    for (int mi = 0; mi < 2; ++mi) {
        f32x16 a = accT[mi];
        float rsum = 0.f;
#pragma unroll
        for (int r = 0; r < 16; ++r) {
            float e = __expf((a[r] - 1.0f) * invT);
            if (dBlk) {
                int grow = wn * 32 + (r & 3) + 8 * (r >> 2) + 4 * h2;
                int gcol = wm * 64 + mi * 32 + c31;
                if (grow == gcol) e = 0.f;
            }
            rsum += e;
        }
        rsum += __shfl_xor(rsum, 32);
        if (h2 == 0) atomicAdd(&rs_l[wm * 64 + mi * 32 + c31], rsum);
    }
    __syncthreads();
    if (tid < 128) atomicAdd(&row_sum[bm * 128 + tid], rs_l[tid]);
    else if (tid < 256) atomicAdd(&col_sum[bn * 128 + (tid - 128)], cs_l[tid - 128]);
}

// loss = mean_i [ 2M + log(rs_i) + log(cs_i) - 2*diag_i ],  M = 1/temp
// 16 blocks x 512 threads; block sums atomicAdd into out[0] (pre-zeroed).
__global__ void finalize_kernel(const float* __restrict__ rs, const float* __restrict__ cs,
                                const float* __restrict__ dg, const float* __restrict__ temp,
                                float* __restrict__ out) {
    const float M = 1.0f / temp[0];
    const int i = blockIdx.x * 512 + threadIdx.x;
    float acc = 2.f * M + __logf(rs[i]) + __logf(cs[i]) - 2.f * dg[i];
#pragma unroll
    for (int s = 1; s < 64; s <<= 1) acc += __shfl_xor(acc, s);
    __shared__ float wsum[8];
    if ((threadIdx.x & 63) == 0) wsum[threadIdx.x >> 6] = acc;
    __syncthreads();
    if (threadIdx.x == 0) {
        float t = 0.f;
#pragma unroll
        for (int w = 0; w < 8; ++w) t += wsum[w];
        atomicAdd(out, t / (float)N_ROWS);
    }
}

extern "C" void kernel_launch(void* const* d_in, const int* in_sizes, int n_in,
                              void* d_out, int out_size, void* d_ws, size_t ws_size,
                              hipStream_t stream) {
    const float* cxr = (const float*)d_in[0];
    const float* ehr = (const float*)d_in[1];
    const float* temp = (const float*)d_in[2];
    float* out = (float*)d_out;

    char* ws = (char*)d_ws;
    unsigned char* Ab = (unsigned char*)ws;                        // 4 MB
    unsigned char* Bb = (unsigned char*)(ws + 4u * 1024 * 1024);   // 4 MB
    float* rs = (float*)(ws + 8u * 1024 * 1024);
    float* cs = rs + N_ROWS;
    float* dg = cs + N_ROWS;

    hipMemsetAsync(rs, 0, 2 * N_ROWS * sizeof(float), stream);
    hipMemsetAsync(out, 0, sizeof(float), stream);
    normdiag_kernel<<<dim3(N_ROWS / 4), 256, 0, stream>>>(cxr, ehr, Ab, Bb, temp, dg);
    gemm_lse_kernel<<<dim3(64 * 64), 512, 0, stream>>>(Ab, Bb, temp, rs, cs);
    finalize_kernel<<<dim3(16), 512, 0, stream>>>(rs, cs, dg, temp, out);
}

// Round 20
// 96.502 us; speedup vs baseline: 1.0777x; 1.0073x over previous
//
#include <hip/hip_runtime.h>
#include <hip/hip_bf16.h>

#define N_ROWS 8192
#define D_DIM  512
#define NSTEPS 8    // K-steps of BK=64 fp8 bytes

typedef __attribute__((ext_vector_type(4))) int   i32x4;
typedef __attribute__((ext_vector_type(8))) int   i32x8;
typedef __attribute__((ext_vector_type(16))) float f32x16;

typedef const __attribute__((address_space(1))) void* gptr_t;
typedef __attribute__((address_space(3))) void* lptr_t;

static __device__ __forceinline__ void gload16(const void* g, void* l) {
    __builtin_amdgcn_global_load_lds((gptr_t)g, (lptr_t)l, 16, 0, 0);
}
#define VMCNT(n)  asm volatile("s_waitcnt vmcnt(" #n ")" ::: "memory")
#define BARRIER() __builtin_amdgcn_s_barrier()
#define SCHED0()  __builtin_amdgcn_sched_barrier(0)

// One wave per row-index i: L2-normalize cxr_i and ehr_i, write fp8 e4m3,
// and compute diag_i = dot(cxr_i,ehr_i)*ia*ib/temp (full fp32) in one pass.
__global__ void normdiag_kernel(const float* __restrict__ cxr, const float* __restrict__ ehr,
                                unsigned char* __restrict__ Ab, unsigned char* __restrict__ Bb,
                                const float* __restrict__ temp, float* __restrict__ dg) {
    const int row = blockIdx.x * 4 + (threadIdx.x >> 6);
    const int lane = threadIdx.x & 63;
    const float4* a4 = (const float4*)(cxr + (size_t)row * D_DIM + lane * 8);
    const float4* b4 = (const float4*)(ehr + (size_t)row * D_DIM + lane * 8);
    float4 a0 = a4[0], a1 = a4[1];
    float4 b0 = b4[0], b1 = b4[1];
    float sa = a0.x*a0.x + a0.y*a0.y + a0.z*a0.z + a0.w*a0.w
             + a1.x*a1.x + a1.y*a1.y + a1.z*a1.z + a1.w*a1.w;
    float sb = b0.x*b0.x + b0.y*b0.y + b0.z*b0.z + b0.w*b0.w
             + b1.x*b1.x + b1.y*b1.y + b1.z*b1.z + b1.w*b1.w;
    float dt = a0.x*b0.x + a0.y*b0.y + a0.z*b0.z + a0.w*b0.w
             + a1.x*b1.x + a1.y*b1.y + a1.z*b1.z + a1.w*b1.w;
#pragma unroll
    for (int s = 1; s < 64; s <<= 1) {
        sa += __shfl_xor(sa, s);
        sb += __shfl_xor(sb, s);
        dt += __shfl_xor(dt, s);
    }
    const float ia = 1.0f / sqrtf(fmaxf(sa, 1e-16f));
    const float ib = 1.0f / sqrtf(fmaxf(sb, 1e-16f));
    if (lane == 0) dg[row] = dt * ia * ib / temp[0];
    float va[8] = {a0.x, a0.y, a0.z, a0.w, a1.x, a1.y, a1.z, a1.w};
    float vb[8] = {b0.x, b0.y, b0.z, b0.w, b1.x, b1.y, b1.z, b1.w};
    int aw0 = __builtin_amdgcn_cvt_pk_fp8_f32(va[0]*ia, va[1]*ia, 0, false);
    aw0     = __builtin_amdgcn_cvt_pk_fp8_f32(va[2]*ia, va[3]*ia, aw0, true);
    int aw1 = __builtin_amdgcn_cvt_pk_fp8_f32(va[4]*ia, va[5]*ia, 0, false);
    aw1     = __builtin_amdgcn_cvt_pk_fp8_f32(va[6]*ia, va[7]*ia, aw1, true);
    int bw0 = __builtin_amdgcn_cvt_pk_fp8_f32(vb[0]*ib, vb[1]*ib, 0, false);
    bw0     = __builtin_amdgcn_cvt_pk_fp8_f32(vb[2]*ib, vb[3]*ib, bw0, true);
    int bw1 = __builtin_amdgcn_cvt_pk_fp8_f32(vb[4]*ib, vb[5]*ib, 0, false);
    bw1     = __builtin_amdgcn_cvt_pk_fp8_f32(vb[6]*ib, vb[7]*ib, bw1, true);
    *(int2*)(Ab + (size_t)row * D_DIM + lane * 8) = make_int2(aw0, aw1);
    *(int2*)(Bb + (size_t)row * D_DIM + lane * 8) = make_int2(bw0, bw1);
}

// by-value 32-byte fragment from two 16-B LDS slots (the r9/r10 no-alloca idiom)
static __device__ __forceinline__ i32x8 ld2(const unsigned char* p0, const unsigned char* p1) {
    i32x4 lo = *(const i32x4*)p0;
    i32x4 hi = *(const i32x4*)(p1);
    return (i32x8){lo[0], lo[1], lo[2], lo[3], hi[0], hi[1], hi[2], hi[3]};
}

// fp8 128x128 GEMM, E + E^T per wave (lane-local row AND col sums) — the r14/
// r19 85us configuration. r20 single delta: s_setprio(1)/(0) around the MFMA
// cluster (T5; role-diverse waves exist via 3 independent block domains/CU).
__global__ __launch_bounds__(512, 2) void gemm_lse_kernel(
        const unsigned char* __restrict__ A, const unsigned char* __restrict__ B,
        const float* __restrict__ temp,
        float* __restrict__ row_sum, float* __restrict__ col_sum) {
    __shared__ unsigned char As[3][8192];    // [buf][128 rows][64 B] = 3 x 8 KB
    __shared__ unsigned char Bs[3][8192];
    __shared__ float rs_l[128];
    __shared__ float cs_l[128];

    const int tid = threadIdx.x;
    const int lane = tid & 63;
    const int wid = tid >> 6;                 // 8 waves
    const int bm = blockIdx.x & 63;           // bm-major for B-panel L2 reuse
    const int bn = blockIdx.x >> 6;
    const int wm = wid >> 2, wn = wid & 3;    // wave tile 64x32

    if (tid < 128) rs_l[tid] = 0.f;
    else if (tid < 256) cs_l[tid - 128] = 0.f;

    // staging: wave stages A rows wid*16..+16 and B rows wid*16..+16 (1 gload
    // each). Linear LDS dest; T2 source swizzle: lane l -> row base+(l>>2),
    // slot l&3, source slot (l&3)^((l>>3)&3).
    const int swz = ((lane & 3) ^ ((lane >> 3) & 3)) * 16;
    const unsigned char* gA = A + (size_t)(bm * 128 + wid * 16 + (lane >> 2)) * D_DIM + swz;
    const unsigned char* gB = B + (size_t)(bn * 128 + wid * 16 + (lane >> 2)) * D_DIM + swz;

#define STG(d, st) do { \
    gload16(gA + (st) * 64, &As[d][(wid * 16) * 64]); \
    gload16(gB + (st) * 64, &Bs[d][(wid * 16) * 64]); } while (0)

    // fragment reads: lane covers row base+c31, k-half h2 (32 B = 2 b128).
    // LDS slot of global slot g at row r: g ^ ((r>>1)&3); (r>>1)&3 = (c31>>1)&3.
    const int c31 = lane & 31, h2 = lane >> 5;
    const int so0 = (((2 * h2) ^ ((c31 >> 1) & 3)) & 3) * 16;

    f32x16 acc[2] = {};    // E quadrants (mi)
    f32x16 accT[2] = {};   // E^T quadrants (mi)
    const int sc = 0x7F7F7F7F;   // E8M0 127 -> scale 1.0

    // prologue: stage steps 0,1 (2 gloads/wave each); drain step 0, keep 1 flying
    STG(0, 0);
    STG(1, 1);
    VMCNT(2);
    BARRIER(); SCHED0();

#pragma unroll
    for (int s = 0; s < NSTEPS; ++s) {
        const int d = s % 3;
        if (s + 2 < NSTEPS) STG((s + 2) % 3, s + 2);

        i32x8 Af0, Af1, Bf;
        {
            const unsigned char* rp = &As[d][(wm * 64 + c31) * 64];
            Af0 = ld2(rp + so0, rp + (so0 ^ 16));
            rp += 32 * 64;
            Af1 = ld2(rp + so0, rp + (so0 ^ 16));
            const unsigned char* bp = &Bs[d][(wn * 32 + c31) * 64];
            Bf = ld2(bp + so0, bp + (so0 ^ 16));
        }
        __builtin_amdgcn_s_setprio(1);
        acc[0]  = __builtin_amdgcn_mfma_scale_f32_32x32x64_f8f6f4(Af0, Bf, acc[0],  0, 0, 0, sc, 0, sc);
        acc[1]  = __builtin_amdgcn_mfma_scale_f32_32x32x64_f8f6f4(Af1, Bf, acc[1],  0, 0, 0, sc, 0, sc);
        accT[0] = __builtin_amdgcn_mfma_scale_f32_32x32x64_f8f6f4(Bf, Af0, accT[0], 0, 0, 0, sc, 0, sc);
        accT[1] = __builtin_amdgcn_mfma_scale_f32_32x32x64_f8f6f4(Bf, Af1, accT[1], 0, 0, 0, sc, 0, sc);
        __builtin_amdgcn_s_setprio(0);

        // boundary: certify step s+1 landed for all waves; keep s+2 flying
        if (s <= NSTEPS - 3)       { VMCNT(2); BARRIER(); SCHED0(); }
        else if (s == NSTEPS - 2)  { VMCNT(0); BARRIER(); SCHED0(); }
    }

    // ---- epilogue: lane-local sums, no shuffle storm (r14 form, __expf) ----
    // C/D 32x32 layout: col = lane&31, row = (reg&3) + 8*(reg>>2) + 4*(lane>>5)
    const float invT = 1.0f / temp[0];
    const bool dBlk = (bm == bn);

    // E: lane owns col j = wn*32 + c31; rows i = wm*64 + mi*32 + rowof(r,h2)
    float csum = 0.f;
#pragma unroll
    for (int mi = 0; mi < 2; ++mi) {
        f32x16 a = acc[mi];
#pragma unroll
        for (int r = 0; r < 16; ++r) {
            float e = __expf((a[r] - 1.0f) * invT);
            if (dBlk) {
                int grow = wm * 64 + mi * 32 + (r & 3) + 8 * (r >> 2) + 4 * h2;
                int gcol = wn * 32 + c31;
                if (grow == gcol) e = 0.f;
            }
            csum += e;
        }
    }
    csum += __shfl_xor(csum, 32);
    if (h2 == 0) atomicAdd(&cs_l[wn * 32 + c31], csum);

    // E^T: lane owns col i = wm*64 + mi*32 + c31; rows j = wn*32 + rowof(r,h2)
#pragma unroll
    for (int mi = 0; mi < 2; ++mi) {
        f32x16 a = accT[mi];
        float rsum = 0.f;
#pragma unroll
        for (int r = 0; r < 16; ++r) {
            float e = __expf((a[r] - 1.0f) * invT);
            if (dBlk) {
                int grow = wn * 32 + (r & 3) + 8 * (r >> 2) + 4 * h2;
                int gcol = wm * 64 + mi * 32 + c31;
                if (grow == gcol) e = 0.f;
            }
            rsum += e;
        }
        rsum += __shfl_xor(rsum, 32);
        if (h2 == 0) atomicAdd(&rs_l[wm * 64 + mi * 32 + c31], rsum);
    }
    __syncthreads();
    if (tid < 128) atomicAdd(&row_sum[bm * 128 + tid], rs_l[tid]);
    else if (tid < 256) atomicAdd(&col_sum[bn * 128 + (tid - 128)], cs_l[tid - 128]);
}

// loss = mean_i [ 2M + log(rs_i) + log(cs_i) - 2*diag_i ],  M = 1/temp
// 16 blocks x 512 threads; block sums atomicAdd into out[0] (pre-zeroed).
__global__ void finalize_kernel(const float* __restrict__ rs, const float* __restrict__ cs,
                                const float* __restrict__ dg, const float* __restrict__ temp,
                                float* __restrict__ out) {
    const float M = 1.0f / temp[0];
    const int i = blockIdx.x * 512 + threadIdx.x;
    float acc = 2.f * M + __logf(rs[i]) + __logf(cs[i]) - 2.f * dg[i];
#pragma unroll
    for (int s = 1; s < 64; s <<= 1) acc += __shfl_xor(acc, s);
    __shared__ float wsum[8];
    if ((threadIdx.x & 63) == 0) wsum[threadIdx.x >> 6] = acc;
    __syncthreads();
    if (threadIdx.x == 0) {
        float t = 0.f;
#pragma unroll
        for (int w = 0; w < 8; ++w) t += wsum[w];
        atomicAdd(out, t / (float)N_ROWS);
    }
}

extern "C" void kernel_launch(void* const* d_in, const int* in_sizes, int n_in,
                              void* d_out, int out_size, void* d_ws, size_t ws_size,
                              hipStream_t stream) {
    const float* cxr = (const float*)d_in[0];
    const float* ehr = (const float*)d_in[1];
    const float* temp = (const float*)d_in[2];
    float* out = (float*)d_out;

    char* ws = (char*)d_ws;
    unsigned char* Ab = (unsigned char*)ws;                        // 4 MB
    unsigned char* Bb = (unsigned char*)(ws + 4u * 1024 * 1024);   // 4 MB
    float* rs = (float*)(ws + 8u * 1024 * 1024);
    float* cs = rs + N_ROWS;
    float* dg = cs + N_ROWS;

    hipMemsetAsync(rs, 0, 2 * N_ROWS * sizeof(float), stream);
    hipMemsetAsync(out, 0, sizeof(float), stream);
    normdiag_kernel<<<dim3(N_ROWS / 4), 256, 0, stream>>>(cxr, ehr, Ab, Bb, temp, dg);
    gemm_lse_kernel<<<dim3(64 * 64), 512, 0, stream>>>(Ab, Bb, temp, rs, cs);
    finalize_kernel<<<dim3(16), 512, 0, stream>>>(rs, cs, dg, temp, out);
}